// Round 16
// baseline (192.766 us; speedup 1.0000x reference)
//
#include <hip/hip_runtime.h>
#include <hip/hip_bf16.h>

#define NAG 256
#define HID 128
#define ACT 5
#define NH 4
#define DD 144      // concat dim
#define EE 576      // embed dim
#define HDIM 144    // per-head dim
#define CMAX 20     // fast-path neighbor cap

// ---------------------------------------------------------------------------
// Wave-split-K GEMM: out[z][256 x N] = A[z][256 x 576] @ W[z][576 x N]
//   (+ bscale[row]*b[z][col]).
// Block: 8 rows x 64 cols; 4 waves each take Kc=144; LDS reduce merges.
// G=36 W scalars double-buffered in regs -> chain = NG=4 latencies.
// ---------------------------------------------------------------------------
template<int KDIM>
__global__ __launch_bounds__(256) void k_gemmK(
    const float* __restrict__ A0, const float* __restrict__ A1, const float* __restrict__ A2,
    const float* __restrict__ W0, const float* __restrict__ W1, const float* __restrict__ W2,
    const float* __restrict__ bb0, const float* __restrict__ bb1, const float* __restrict__ bb2,
    const float* __restrict__ bscale,
    float* __restrict__ o0, float* __restrict__ o1, float* __restrict__ o2,
    int N, int NX)
{
    constexpr int Kc = KDIM / 4;               // per-wave K chunk (144)
    constexpr int G  = 36;
    constexpr int NG = Kc / G;                 // 4
    constexpr int LDA = KDIM + 4;
    __shared__ union { float As[8 * LDA]; float red[2048]; } sm;

    const int perz = NX * 32;
    const int b = blockIdx.x;
    const int z = b / perz, rem = b % perz;
    const int bx = rem >> 5, mb = rem & 31;
    const float* A   = (z == 0) ? A0  : (z == 1) ? A1  : A2;
    const float* W   = (z == 0) ? W0  : (z == 1) ? W1  : W2;
    const float* bia = (z == 0) ? bb0 : (z == 1) ? bb1 : bb2;
    float*       out = (z == 0) ? o0  : (z == 1) ? o1  : o2;
    const int tid = threadIdx.x;

    for (int idx = tid; idx < 8 * (KDIM / 4); idx += 256) {
        int r = idx / (KDIM / 4), c = idx % (KDIM / 4);
        *((float4*)&sm.As[r * LDA + c * 4]) =
            *(const float4*)(A + (size_t)(mb * 8 + r) * KDIM + c * 4);
    }
    __syncthreads();

    const int wave = tid >> 6, lane = tid & 63;
    const int colg = bx * 64 + lane;
    const bool cv = colg < N;
    const int colc = cv ? colg : (N - 1);
    const float* Wp = W + (size_t)(wave * Kc) * N + colc;
    float acc[8] = {};
    float wv[G], wn[G];
    #pragma unroll
    for (int j = 0; j < G; ++j) wv[j] = Wp[(size_t)j * N];
    for (int g = 0; g < NG; ++g) {
        if (g + 1 < NG) {
            const float* Wn = Wp + (size_t)(g + 1) * G * N;
            #pragma unroll
            for (int j = 0; j < G; ++j) wn[j] = Wn[(size_t)j * N];
        }
        const int kb = wave * Kc + g * G;
        #pragma unroll
        for (int j4 = 0; j4 < G / 4; ++j4) {
            #pragma unroll
            for (int r = 0; r < 8; ++r) {
                float4 a4 = *(const float4*)&sm.As[r * LDA + kb + j4 * 4];
                acc[r] += a4.x * wv[j4 * 4 + 0] + a4.y * wv[j4 * 4 + 1]
                        + a4.z * wv[j4 * 4 + 2] + a4.w * wv[j4 * 4 + 3];
            }
        }
        #pragma unroll
        for (int j = 0; j < G; ++j) wv[j] = wn[j];
    }
    __syncthreads();                           // all waves done reading As
    #pragma unroll
    for (int r = 0; r < 8; ++r) sm.red[wave * 512 + r * 64 + lane] = acc[r];
    __syncthreads();
    #pragma unroll
    for (int q = 0; q < 2; ++q) {
        int idx = tid + q * 256;               // 512 outputs
        int r = idx >> 6, cl = idx & 63;
        int col = bx * 64 + cl;
        if (col < N) {
            float s = sm.red[idx] + sm.red[512 + idx]
                    + sm.red[1024 + idx] + sm.red[1536 + idx];
            int row = mb * 8 + r;
            float bs = bscale ? bscale[row] : 1.f;
            float bb = bia ? bia[col] : 0.f;
            out[(size_t)row * N + col] = s + bs * bb;
        }
    }
}

// ---------------------------------------------------------------------------
// gemm1 (fused obs-encoder) + L2/L3 warming of gemm2's weights.
// Blocks 0..863: Ct = concat(enc(hidden), action) in LDS; out = Ct@W_z + b_z;
//   K-loop = one group of 36 reg-loads per wave (Kc=36).
// Blocks 864..1119 (warm): stream Wiq/Wik/Wiv into cache (no barriers).
// ---------------------------------------------------------------------------
__global__ __launch_bounds__(256) void k_gemm1(
    const float* __restrict__ hidden, const float* __restrict__ action,
    const float* __restrict__ W_enc, const float* __restrict__ b_enc,
    const float* __restrict__ Wq, const float* __restrict__ Wk, const float* __restrict__ Wv,
    const float* __restrict__ bq, const float* __restrict__ bk, const float* __restrict__ bv,
    const float* __restrict__ Wiq, const float* __restrict__ Wik, const float* __restrict__ Wiv,
    float* __restrict__ tq, float* __restrict__ tk, float* __restrict__ tv,
    float* __restrict__ sink)
{
    const int b = blockIdx.x;
    const int tid = threadIdx.x;
    if (b >= 864) {                            // warming branch (block-uniform)
        const int wb = b - 864;                // 0..255
        float s = 0.f;
        // each matrix: 82944 float4; 324 per block; ~1.27 per thread
        for (int m = 0; m < 3; ++m) {
            const float* Wm = (m == 0) ? Wiq : (m == 1) ? Wik : Wiv;
            const float4* W4 = (const float4*)Wm;
            for (int idx = wb * 324 + tid; idx < (wb + 1) * 324 && idx < 82944; idx += 256) {
                float4 v4 = W4[idx];
                s += v4.x + v4.y + v4.z + v4.w;
            }
        }
        if (s == 123456789.0f) sink[0] = s;    // never true; defeats DCE
        return;
    }
    __shared__ float Ct[8][148];
    __shared__ union { struct { float Hs[8][132]; float We[2048]; } e;
                       float red[2048]; } u;
    const int z = b / 288, rem = b % 288;
    const int bx = rem >> 5, mb = rem & 31;
    const float* W  = (z == 0) ? Wq : (z == 1) ? Wk : Wv;
    const float* bi = (z == 0) ? bq : (z == 1) ? bk : bv;
    float*      out = (z == 0) ? tq : (z == 1) ? tk : tv;

    {   // stage hidden rows, W_enc, action
        int r = tid >> 5, kq = tid & 31;
        *((float4*)&u.e.Hs[r][kq * 4]) =
            *(const float4*)(hidden + (mb * 8 + r) * HID + kq * 4);
        *((float4*)&Ct[r][16 + kq * 4]) =
            *(const float4*)(action + (mb * 8 + r) * HID + kq * 4);
        *((float4*)&u.e.We[tid * 4])        = *(const float4*)(W_enc + tid * 4);
        *((float4*)&u.e.We[1024 + tid * 4]) = *(const float4*)(W_enc + 1024 + tid * 4);
    }
    __syncthreads();
    if (tid < 128) {                           // enc: 8 rows x 16 outs (LDS only)
        int r = tid >> 4, o = tid & 15;
        float acc = 0.f;
        #pragma unroll 8
        for (int d = 0; d < HID; ++d) acc += u.e.Hs[r][d] * u.e.We[d * 16 + o];
        Ct[r][o] = acc + b_enc[o];
    }
    __syncthreads();

    constexpr int Kc = 36, G = 36;             // single load group
    const int wave = tid >> 6, lane = tid & 63;
    const int colg = bx * 64 + lane;
    const float* Wp = W + (size_t)(wave * Kc) * EE + colg;
    float acc[8] = {};
    float wv[G];
    #pragma unroll
    for (int j = 0; j < G; ++j) wv[j] = Wp[(size_t)j * EE];
    const int kb = wave * Kc;
    #pragma unroll
    for (int j4 = 0; j4 < G / 4; ++j4) {
        #pragma unroll
        for (int r = 0; r < 8; ++r) {
            float4 a4 = *(const float4*)&Ct[r][kb + j4 * 4];
            acc[r] += a4.x * wv[j4 * 4 + 0] + a4.y * wv[j4 * 4 + 1]
                    + a4.z * wv[j4 * 4 + 2] + a4.w * wv[j4 * 4 + 3];
        }
    }
    __syncthreads();                           // Hs/We dead; red overlays
    #pragma unroll
    for (int r = 0; r < 8; ++r) u.red[wave * 512 + r * 64 + lane] = acc[r];
    __syncthreads();
    #pragma unroll
    for (int q = 0; q < 2; ++q) {
        int idx = tid + q * 256;
        int r = idx >> 6, cl = idx & 63;
        int col = bx * 64 + cl;
        float s = u.red[idx] + u.red[512 + idx]
                + u.red[1024 + idx] + u.red[1536 + idx];
        out[(size_t)(mb * 8 + r) * EE + col] = s + bi[col];
    }
}

// ---------------------------------------------------------------------------
// Fused scores + attention (blocks 0..255) + warming of Wo/W_O (256..511).
// ---------------------------------------------------------------------------
__global__ __launch_bounds__(256) void k_attn(
    const int* __restrict__ state, const float* __restrict__ q,
    const float* __restrict__ kmat, const float* __restrict__ v,
    const float* __restrict__ Wo, const float* __restrict__ W_O,
    float* __restrict__ ctxsum, float* __restrict__ cnt,
    float* __restrict__ sink)
{
    const int blk = blockIdx.x, tid = threadIdx.x;
    if (blk >= NAG) {                          // warming branch (block-uniform)
        const int wb = blk - NAG;              // 0..255
        float s = 0.f;
        const float4* W4 = (const float4*)Wo;  // 82944 float4
        for (int idx = wb * 324 + tid; idx < (wb + 1) * 324 && idx < 82944; idx += 256) {
            float4 v4 = W4[idx];
            s += v4.x + v4.y + v4.z + v4.w;
        }
        const float4* O4 = (const float4*)W_O; // 20736 float4
        for (int idx = wb * 81 + tid; idx < (wb + 1) * 81 && idx < 20736; idx += 256) {
            float4 v4 = O4[idx];
            s += v4.x + v4.y + v4.z + v4.w;
        }
        if (s == 123456789.0f) sink[1] = s;
        return;
    }
    __shared__ int lst[NAG];
    __shared__ int cnt_s;
    __shared__ float w4[NH][NAG];
    __shared__ float qh[CMAX][HDIM + 1];
    __shared__ float kh[CMAX][HDIM + 1];
    __shared__ float Sl[CMAX][CMAX + 1];
    const int i = blk;
    if (tid == 0) cnt_s = 0;
    __syncthreads();
    {
        int xi = state[2 * i], yi = state[2 * i + 1];
        int xj = state[2 * tid], yj = state[2 * tid + 1];
        int dx = xi - xj; if (dx < 0) dx = -dx;
        int dy = yi - yj; if (dy < 0) dy = -dy;
        if (tid > i && dx <= 4 && dy <= 2) {
            int p = atomicAdd(&cnt_s, 1);
            lst[p] = tid;
        }
    }
    __syncthreads();
    const int c = cnt_s;                 // block-uniform
    if (tid == 0) cnt[i] = (float)c;
    if (c == 0) {
        for (int e = tid; e < EE; e += 256) ctxsum[i * EE + e] = 0.f;
        return;
    }
    if (c <= CMAX) {
        for (int h = 0; h < NH; ++h) {
            for (int idx = tid; idx < c * HDIM; idx += 256) {
                int jj = idx / HDIM, d = idx % HDIM;
                qh[jj][d] = q[lst[jj] * EE + h * HDIM + d];
                kh[jj][d] = kmat[lst[jj] * EE + h * HDIM + d];
            }
            __syncthreads();
            for (int pp = tid; pp < c * c; pp += 256) {
                int jj = pp / c, kk = pp % c;
                float acc = 0.f;
                for (int d = 0; d < HDIM; ++d) acc += qh[jj][d] * kh[kk][d];
                Sl[jj][kk] = acc * (1.0f / 12.0f);
            }
            __syncthreads();
            if (tid < c) {
                float m = -1e30f;
                for (int kk = 0; kk < c; ++kk) m = fmaxf(m, Sl[tid][kk]);
                float zz = 0.f;
                for (int kk = 0; kk < c; ++kk) zz += __expf(Sl[tid][kk] - m);
                float inv = 1.f / fmaxf(zz, 1e-9f);
                for (int kk = 0; kk < c; ++kk)
                    Sl[tid][kk] = __expf(Sl[tid][kk] - m) * inv;
            }
            __syncthreads();
            if (tid < c) {
                float s = 0.f;
                for (int jj = 0; jj < c; ++jj) s += Sl[jj][tid];
                w4[h][tid] = s;
            }
            __syncthreads();
        }
    } else {
        for (int idx = tid; idx < NH * c; idx += 256) w4[idx / c][idx % c] = 0.f;
        __syncthreads();
        for (int pnh = tid; pnh < NH * c; pnh += 256) {
            int h = pnh / c, jj = pnh % c;
            const float* qrow = q + lst[jj] * EE + h * HDIM;
            float m = -1e30f;
            for (int kk = 0; kk < c; ++kk) {
                const float* krow = kmat + lst[kk] * EE + h * HDIM;
                float a = 0.f;
                for (int d = 0; d < HDIM; ++d) a += qrow[d] * krow[d];
                m = fmaxf(m, a * (1.0f / 12.0f));
            }
            float zz = 0.f;
            for (int kk = 0; kk < c; ++kk) {
                const float* krow = kmat + lst[kk] * EE + h * HDIM;
                float a = 0.f;
                for (int d = 0; d < HDIM; ++d) a += qrow[d] * krow[d];
                zz += __expf(a * (1.0f / 12.0f) - m);
            }
            float inv = 1.f / fmaxf(zz, 1e-9f);
            for (int kk = 0; kk < c; ++kk) {
                const float* krow = kmat + lst[kk] * EE + h * HDIM;
                float a = 0.f;
                for (int d = 0; d < HDIM; ++d) a += qrow[d] * krow[d];
                atomicAdd(&w4[h][kk], __expf(a * (1.0f / 12.0f) - m) * inv);
            }
        }
        __syncthreads();
    }
    for (int e = tid; e < EE; e += 256) {
        int h = e / HDIM;
        float a0 = 0.f, a1 = 0.f;
        int t = 0;
        for (; t + 1 < c; t += 2) {
            a0 += w4[h][t] * v[lst[t] * EE + e];
            a1 += w4[h][t + 1] * v[lst[t + 1] * EE + e];
        }
        if (t < c) a0 += w4[h][t] * v[lst[t] * EE + e];
        ctxsum[i * EE + e] = a0 + a1;
    }
}

// ---------------------------------------------------------------------------
// Dueling head: per agent i, 64 threads.
// ---------------------------------------------------------------------------
__global__ __launch_bounds__(64) void k_head(
    const float* __restrict__ hb,
    const float* __restrict__ W_val, const float* __restrict__ b_val,
    const float* __restrict__ W_adv, const float* __restrict__ b_adv,
    float* __restrict__ out)
{
    const int i = blockIdx.x, t = threadIdx.x;
    const float* hr = hb + i * DD;
    float h0 = hr[t], h1 = hr[t + 64];
    float h2 = (t < 16) ? hr[t + 128] : 0.f;
    float red[6];
    for (int o = 0; o < 6; ++o) {
        float p;
        if (o < 5) {
            p = h0 * W_adv[t * ACT + o] + h1 * W_adv[(t + 64) * ACT + o];
            if (t < 16) p += h2 * W_adv[(t + 128) * ACT + o];
        } else {
            p = h0 * W_val[t] + h1 * W_val[t + 64];
            if (t < 16) p += h2 * W_val[t + 128];
        }
        for (int off = 32; off; off >>= 1) p += __shfl_xor(p, off);
        red[o] = p;
    }
    if (t == 0) {
        float a[ACT], mean = 0.f;
        for (int o = 0; o < ACT; ++o) { a[o] = red[o] + b_adv[o]; mean += a[o]; }
        mean *= (1.0f / ACT);
        float V = red[5] + b_val[0];
        for (int o = 0; o < ACT; ++o) out[i * ACT + o] = V + a[o] - mean;
    }
}

// ---------------------------------------------------------------------------
extern "C" void kernel_launch(void* const* d_in, const int* in_sizes, int n_in,
                              void* d_out, int out_size, void* d_ws, size_t ws_size,
                              hipStream_t stream)
{
    const float* hidden = (const float*)d_in[0];
    const float* action = (const float*)d_in[1];
    const int*   state  = (const int*)d_in[2];

    float* ws = (float*)d_ws;
    float* tq   = ws;                        // 256*576 each
    float* tk   = tq   + NAG * EE;
    float* tv   = tk   + NAG * EE;
    float* q    = tv   + NAG * EE;
    float* kb   = q    + NAG * EE;
    float* v    = kb   + NAG * EE;
    float* ctx  = v    + NAG * EE;
    float* cnt  = ctx  + NAG * EE;           // 256
    float* hbuf = cnt  + NAG;                // 256*144
    float* sink = hbuf + NAG * DD;           // 2 (warming DCE sink)
    float* tout = tq;                        // alias: tq dead after gemm2
    // total ws ~4.3 MB

    // gemm1 (fused enc) + warm gemm2 weights: 864 compute + 256 warming blocks
    k_gemm1<<<1120, 256, 0, stream>>>(hidden, action,
        (const float*)d_in[3], (const float*)d_in[4],
        (const float*)d_in[5], (const float*)d_in[7], (const float*)d_in[9],
        (const float*)d_in[6], (const float*)d_in[8], (const float*)d_in[10],
        (const float*)d_in[11], (const float*)d_in[13], (const float*)d_in[15],
        tq, tk, tv, sink);

    // gemm2: {q,k,v} = t @ Wi* + bi  (K=576, N=576, 3z, 864 blocks)
    k_gemmK<576><<<864, 256, 0, stream>>>(tq, tk, tv,
        (const float*)d_in[11], (const float*)d_in[13], (const float*)d_in[15],
        (const float*)d_in[12], (const float*)d_in[14], (const float*)d_in[16],
        nullptr, q, kb, v, EE, 9);

    // fused scores+attention (256) + warm Wo/W_O (256)
    k_attn<<<512, 256, 0, stream>>>(state, q, kb, v,
        (const float*)d_in[17], (const float*)d_in[19], ctx, cnt, sink);

    // gemm3: tout = ctx @ Wo + cnt*bo  (K=576, N=576, 288 blocks)
    k_gemmK<576><<<288, 256, 0, stream>>>(ctx, ctx, ctx,
        (const float*)d_in[17], (const float*)d_in[17], (const float*)d_in[17],
        (const float*)d_in[18], (const float*)d_in[18], (const float*)d_in[18],
        cnt, tout, tout, tout, EE, 9);

    // gemm4: hbuf = tout @ W_O  (K=576, N=144, 96 blocks, no bias)
    k_gemmK<576><<<96, 256, 0, stream>>>(tout, tout, tout,
        (const float*)d_in[19], (const float*)d_in[19], (const float*)d_in[19],
        nullptr, nullptr, nullptr,
        nullptr, hbuf, hbuf, hbuf, DD, 3);

    // head
    k_head<<<NAG, 64, 0, stream>>>(hbuf,
        (const float*)d_in[20], (const float*)d_in[21],
        (const float*)d_in[22], (const float*)d_in[23], (float*)d_out);
}